// Round 4
// baseline (521.945 us; speedup 1.0000x reference)
//
#include <hip/hip_runtime.h>
#include <stdint.h>

// ============================================================================
// Attention_16441134809293 : B=1 T=2048 D=4096 N=32 KV=8 H=128, fp32 in/out.
// Round 7:
//  - k_attn rebuilt: 512 thr / 8 waves x 32 q-rows (two 16-row MFMA sets per
//    wave sharing every K/V B-fragment read -> 2x MFMA per LDS read). Block
//    (p,head): waves 0-3 = rows [128p,128p+128) (nk=p+1), waves 4-7 = mirror
//    rows [128(15-p),..) (nk=16-p); per-block cost constant (288*17 reads).
//    Grid 8x32 = 256 blocks = 1/CU. P in dedicated 64KB LDS (no QK->P
//    barrier): 2 barriers/tile. LDS 128KB dynamic.
//  - gemm kernels unchanged from round 6.
// Workspace map (peak 88 MB):
//   phase1 (gemm1): xb[0,16M) Wt[16,64M) Q[64,80M) K[80,84M) Vt[84,88M)
//   phase2 (attn) : att[0,16M) Ot[16,48M)  (over dead xb/Wt)
// ============================================================================

typedef __bf16 bf16x8 __attribute__((ext_vector_type(8)));
typedef float  f32x4  __attribute__((ext_vector_type(4)));

__device__ __forceinline__ uint16_t f2bf(float f) {
    union { float f; uint32_t u; } v; v.f = f;
    uint32_t r = v.u + 0x7fffu + ((v.u >> 16) & 1u);   // RNE
    return (uint16_t)(r >> 16);
}

__device__ __forceinline__ void gload_lds16(const void* g, void* l) {
    __builtin_amdgcn_global_load_lds(
        (const __attribute__((address_space(1))) uint32_t*)g,
        (__attribute__((address_space(3))) uint32_t*)l, 16, 0, 0);
}

// ------------------------------------------- x -> bf16, swizzled chunk layout
__global__ __launch_bounds__(256) void k_cvt_x(const float* __restrict__ x,
                                               uint16_t* __restrict__ xb) {
    int i = (blockIdx.x * 256 + threadIdx.x) * 8;
    int r = i >> 12, k = i & 4095;
    float4 a = *(const float4*)(x + i);
    float4 b = *(const float4*)(x + i + 4);
    uint16_t tmp[8];
    tmp[0] = f2bf(a.x); tmp[1] = f2bf(a.y); tmp[2] = f2bf(a.z); tmp[3] = f2bf(a.w);
    tmp[4] = f2bf(b.x); tmp[5] = f2bf(b.y); tmp[6] = f2bf(b.z); tmp[7] = f2bf(b.w);
    int dst = r * 4096 + (k & ~63) + (((((k >> 3) & 7) ^ (r & 7))) << 3);
    *(uint4*)(xb + dst) = *(uint4*)tmp;
}

// ---------------- q_w/kv_w -> Wt[c][d] bf16 (B^T layout, c=head*128+h), swizzled
__global__ __launch_bounds__(256) void k_prep_wt(const float* __restrict__ qw,
                                                 const float* __restrict__ kvw,
                                                 uint16_t* __restrict__ Wt) {
    const int hx = blockIdx.x, dx = blockIdx.y, m = blockIdx.z;
    const float* src = (m < 32) ? (qw + (size_t)m * 524288)
                                : (kvw + (size_t)(m - 32) * 524288);
    __shared__ uint16_t tile[64][65];                            // [d][h]
    const int t = threadIdx.x, d0 = dx * 64, h0 = hx * 64;
#pragma unroll
    for (int i = 0; i < 16; ++i) {
        int idx = i * 256 + t, r = idx >> 6, c = idx & 63;
        tile[r][c] = f2bf(src[(size_t)(d0 + r) * 128 + h0 + c]);
    }
    __syncthreads();
#pragma unroll
    for (int it = 0; it < 2; ++it) {
        int slot = it * 256 + t, hr = slot >> 3, cl = slot & 7;
        int R = m * 128 + h0 + hr;
        uint16_t tmp[8];
#pragma unroll
        for (int e = 0; e < 8; ++e) tmp[e] = tile[cl * 8 + e][hr];
        *(uint4*)&Wt[(size_t)R * 4096 + d0 + ((cl ^ (R & 7)) << 3)] = *(uint4*)tmp;
    }
}

// --------------------- o_w[n][h][d] -> Ot[d][n*128+h] bf16 (B^T), swizzled
__global__ __launch_bounds__(256) void k_prep_ot(const float* __restrict__ ow,
                                                 uint16_t* __restrict__ Ot) {
    const int dx = blockIdx.x, hx = blockIdx.y, n = blockIdx.z;
    const float* src = ow + (size_t)n * 524288;                  // [128][4096]
    __shared__ uint16_t tile[64][65];                            // [h][d]
    const int t = threadIdx.x, h0 = hx * 64, d0 = dx * 64;
#pragma unroll
    for (int i = 0; i < 16; ++i) {
        int idx = i * 256 + t, r = idx >> 6, c = idx & 63;
        tile[r][c] = f2bf(src[(size_t)(h0 + r) * 4096 + d0 + c]);
    }
    __syncthreads();
#pragma unroll
    for (int it = 0; it < 2; ++it) {
        int slot = it * 256 + t, dr = slot >> 3, cl = slot & 7;
        int R = d0 + dr;
        uint16_t tmp[8];
#pragma unroll
        for (int e = 0; e < 8; ++e) tmp[e] = tile[cl * 8 + e][dr];
        *(uint4*)&Ot[(size_t)R * 4096 + n * 128 + h0 + ((cl ^ (R & 7)) << 3)] = *(uint4*)tmp;
    }
}

// ---------------------------------------------------------------- sync macros
#define PH_BAR do { asm volatile("" ::: "memory"); \
                    __builtin_amdgcn_s_barrier(); \
                    asm volatile("" ::: "memory"); } while (0)
#define WAIT_VM(N) do { asm volatile("s_waitcnt vmcnt(" #N ")" ::: "memory"); \
                        __builtin_amdgcn_sched_barrier(0); } while (0)
#define SCHED0 __builtin_amdgcn_sched_barrier(0)

// ============================================================================
// gemm1 + fused RMSNorm/RoPE epilogue, 256x256 tile, 8 waves, pipelined.
// (unchanged from round 6)
// ============================================================================
__global__ __launch_bounds__(512, 2) void k_gemm_qkv(const uint16_t* __restrict__ A,
                                                     const uint16_t* __restrict__ Bt,
                                                     const int* __restrict__ pos,
                                                     const float* __restrict__ qs,
                                                     const float* __restrict__ ks,
                                                     uint16_t* __restrict__ Qg,
                                                     uint16_t* __restrict__ Kg,
                                                     uint16_t* __restrict__ Vg) {
    extern __shared__ __align__(16) char smem[];
    uint16_t* lds = (uint16_t*)smem;
    const int Kd = 4096;
    const int t = threadIdx.x, wid = t >> 6, lane = t & 63;
    const int l16 = lane & 15, quad = lane >> 4;
    const int wr = wid >> 2, wc = wid & 3;
    const int bx = blockIdx.x, bm0 = blockIdx.y * 256, bn0 = bx * 256;

    f32x4 acc[8][4];
    const f32x4 z4 = {0.f, 0.f, 0.f, 0.f};
#pragma unroll
    for (int i = 0; i < 8; ++i)
#pragma unroll
        for (int j = 0; j < 4; ++j) acc[i][j] = z4;

    const int r0 = wid * 16 + (lane >> 2), c4 = lane & 3;
    const int sw2 = (r0 >> 1) & 3, sw7 = r0 & 7;
    const int offK0 = (((c4 ^ sw2)) ^ sw7) * 8;
    const int offK1 = ((4 + (c4 ^ sw2)) ^ sw7) * 8;
    const uint16_t* pA0 = A + (size_t)(bm0 + r0) * Kd;
    const uint16_t* pA1 = pA0 + (size_t)128 * Kd;
    const uint16_t* pB0 = Bt + (size_t)(bn0 + r0) * Kd;
    const uint16_t* pB1 = pB0 + (size_t)128 * Kd;
    uint16_t* stA = lds + wid * 512;
    uint16_t* stB = lds + 32768 + wid * 512;

    const int sA = (l16 >> 1) & 3;
    const int rdA = (wr * 128 + l16) * 32 + ((quad ^ sA) << 3);
    const int rdB = 32768 + (wc * 64 + l16) * 32 + ((quad ^ sA) << 3);

    bf16x8 afA[4], afB[4], bfA[4], bfB[4];

#define STAGE_A(SLAB, OFF, TT) do { \
    gload_lds16(pA0 + (size_t)(TT) * 64 + (OFF), stA + (SLAB) * 8192); \
    gload_lds16(pA1 + (size_t)(TT) * 64 + (OFF), stA + (SLAB) * 8192 + 4096); } while (0)
#define STAGE_B(SLAB, OFF, TT) do { \
    gload_lds16(pB0 + (size_t)(TT) * 64 + (OFF), stB + (SLAB) * 8192); \
    gload_lds16(pB1 + (size_t)(TT) * 64 + (OFF), stB + (SLAB) * 8192 + 4096); } while (0)
#define RD_A(DST, SLAB, I0) do { _Pragma("unroll") \
    for (int i_ = 0; i_ < 4; ++i_) \
        DST[i_] = *(const bf16x8*)&lds[(SLAB) * 8192 + rdA + ((I0) + i_) * 512]; } while (0)
#define RD_B(DST, SLAB) do { _Pragma("unroll") \
    for (int j_ = 0; j_ < 4; ++j_) \
        DST[j_] = *(const bf16x8*)&lds[(SLAB) * 8192 + rdB + j_ * 512]; } while (0)
#define MFMA16(AF, BF, I0) do { __builtin_amdgcn_s_setprio(1); \
    _Pragma("unroll") for (int i_ = 0; i_ < 4; ++i_) \
        _Pragma("unroll") for (int j_ = 0; j_ < 4; ++j_) \
            acc[(I0) + i_][j_] = __builtin_amdgcn_mfma_f32_16x16x32_bf16(AF[i_], BF[j_], acc[(I0) + i_][j_], 0, 0, 0); \
    __builtin_amdgcn_s_setprio(0); } while (0)

#define TILE(TT, BUF) do { \
    RD_A(afB, 2*(BUF), 4); \
    WAIT_VM(4); \
    STAGE_A(2*((BUF)^1)+1, offK1, (TT)+1); \
    SCHED0; MFMA16(afA, bfA, 0); PH_BAR; \
    RD_A(afA, 2*(BUF)+1, 0); RD_B(bfB, 2*(BUF)+1); \
    STAGE_B(2*((BUF)^1)+1, offK1, (TT)+1); \
    SCHED0; MFMA16(afB, bfA, 4); PH_BAR; \
    RD_A(afB, 2*(BUF)+1, 4); \
    WAIT_VM(4); \
    STAGE_A(2*(BUF), offK0, (TT)+2); \
    SCHED0; MFMA16(afA, bfB, 0); PH_BAR; \
    RD_A(afA, 2*((BUF)^1), 0); RD_B(bfA, 2*((BUF)^1)); \
    STAGE_B(2*(BUF), offK0, (TT)+2); \
    SCHED0; MFMA16(afB, bfB, 4); PH_BAR; \
} while (0)

    STAGE_A(0, offK0, 0); STAGE_B(0, offK0, 0);
    STAGE_A(1, offK1, 0); STAGE_B(1, offK1, 0);
    STAGE_A(2, offK0, 1); STAGE_B(2, offK0, 1);
    WAIT_VM(8);
    PH_BAR;
    RD_A(afA, 0, 0); RD_B(bfA, 0);

#pragma unroll 1
    for (int Ti = 0; Ti < 31; ++Ti) {
        TILE(2 * Ti, 0);
        TILE(2 * Ti + 1, 1);
    }

    RD_A(afB, 0, 4); WAIT_VM(4); STAGE_A(3, offK1, 63);
    SCHED0; MFMA16(afA, bfA, 0); PH_BAR;
    RD_A(afA, 1, 0); RD_B(bfB, 1); STAGE_B(3, offK1, 63);
    SCHED0; MFMA16(afB, bfA, 4); PH_BAR;
    RD_A(afB, 1, 4); WAIT_VM(4);
    SCHED0; MFMA16(afA, bfB, 0); PH_BAR;
    RD_A(afA, 2, 0); RD_B(bfA, 2);
    SCHED0; MFMA16(afB, bfB, 4); PH_BAR;
    RD_A(afB, 2, 4); WAIT_VM(0);
    SCHED0; MFMA16(afA, bfA, 0); PH_BAR;
    RD_A(afA, 3, 0); RD_B(bfB, 3);
    SCHED0; MFMA16(afB, bfA, 4); PH_BAR;
    RD_A(afB, 3, 4);
    SCHED0; MFMA16(afA, bfB, 0); PH_BAR;
    SCHED0; MFMA16(afB, bfB, 4);

#undef TILE
#undef MFMA16
#undef RD_B
#undef RD_A
#undef STAGE_B
#undef STAGE_A

    float* X   = (float*)smem;
    float* ssq = (float*)(smem + 133120);

#pragma unroll
    for (int i = 0; i < 8; ++i)
#pragma unroll
        for (int r = 0; r < 4; ++r) {
            float s = 0.f;
#pragma unroll
            for (int j = 0; j < 4; ++j) s += acc[i][j][r] * acc[i][j][r];
            s += __shfl_xor(s, 1); s += __shfl_xor(s, 2);
            s += __shfl_xor(s, 4); s += __shfl_xor(s, 8);
            if (l16 == 0)
                ssq[(wr * 128 + i * 16 + quad * 4 + r) * 4 + (wc >> 1) * 2 + (wc & 1)] = s;
        }
    __syncthreads();

    const int cat = (bx < 16) ? 0 : (bx < 20 ? 1 : 2);
    float s1 = 0.f, s2 = 0.f, invts = 0.f;
    if (cat < 2) {
        const float* sc = cat ? ks : qs;
        s1 = 1.0f + sc[lane];
        s2 = 1.0f + sc[lane + 64];
        invts = exp2f((float)lane * -0.20762050593046014f);
    }

#pragma unroll
    for (int pass = 0; pass < 2; ++pass) {
        if (wr == pass) {
#pragma unroll
            for (int i = 0; i < 8; ++i)
#pragma unroll
                for (int j = 0; j < 4; ++j)
#pragma unroll
                    for (int r = 0; r < 4; ++r)
                        X[(i * 16 + quad * 4 + r) * 260 + wc * 64 + j * 16 + l16] = acc[i][j][r];
        }
        __syncthreads();
        for (int rr = 0; rr < 16; ++rr) {
            const int lrow = wid * 16 + rr;
            const int grow = bm0 + pass * 128 + lrow;
            float sn = 0.f, cs = 0.f;
            if (cat < 2) {
                float ang = (float)pos[grow] * invts;
                __sincosf(ang, &sn, &cs);
            }
#pragma unroll
            for (int hh = 0; hh < 2; ++hh) {
                const int sb = (pass * 128 + lrow) * 4 + hh * 2;
                float rn = rsqrtf((ssq[sb] + ssq[sb + 1]) * 0.0078125f + 1e-6f);
                float x1 = X[lrow * 260 + hh * 128 + lane];
                float x2 = X[lrow * 260 + hh * 128 + 64 + lane];
                if (cat < 2) {
                    float y1 = x1 * rn * s1, y2 = x2 * rn * s2;
                    X[lrow * 260 + hh * 128 + lane]      = y1 * cs - y2 * sn;
                    X[lrow * 260 + hh * 128 + 64 + lane] = y2 * cs + y1 * sn;
                } else {
                    X[lrow * 260 + hh * 128 + lane]      = x1 * rn;
                    X[lrow * 260 + hh * 128 + 64 + lane] = x2 * rn;
                }
            }
        }
        __syncthreads();
        if (cat == 2) {
#pragma unroll
            for (int it = 0; it < 8; ++it) {
                int slot = it * 512 + t, hh = slot >> 11, rem = slot & 2047;
                int h = rem >> 4, sc2 = rem & 15;
                uint16_t tmp[8];
#pragma unroll
                for (int e = 0; e < 8; ++e)
                    tmp[e] = f2bf(X[(sc2 * 8 + e) * 260 + hh * 128 + h]);
                int n = bx * 2 + hh;
                *(uint4*)&Vg[((size_t)(n - 40) * 128 + h) * 2048 + (bm0 + pass * 128)
                             + ((sc2 ^ (h & 15)) << 3)] = *(uint4*)tmp;
            }
        } else {
#pragma unroll
            for (int it = 0; it < 8; ++it) {
                int slot = it * 512 + t, hh = slot >> 11, rem = slot & 2047;
                int lrow = rem >> 4, c = rem & 15;
                int tg = bm0 + pass * 128 + lrow, n = bx * 2 + hh;
                f32x4 a = *(f32x4*)&X[lrow * 260 + hh * 128 + c * 8];
                f32x4 b = *(f32x4*)&X[lrow * 260 + hh * 128 + c * 8 + 4];
                uint16_t tmp[8];
#pragma unroll
                for (int e = 0; e < 4; ++e) { tmp[e] = f2bf(a[e]); tmp[4 + e] = f2bf(b[e]); }
                if (cat == 0)
                    *(uint4*)&Qg[((size_t)n * 2048 + tg) * 128 + c * 8] = *(uint4*)tmp;
                else
                    *(uint4*)&Kg[((size_t)(n - 32) * 2048 + tg) * 128
                                 + ((c ^ (tg & 15)) << 3)] = *(uint4*)tmp;
            }
        }
        __syncthreads();
    }
}

// ============================================================================
// gemm2: out = att(2048x4096) * Ot^T(4096x4096), pipelined 256x128 tile.
// (unchanged from round 6)
// ============================================================================
__global__ __launch_bounds__(512, 2) void k_gemm2p(const uint16_t* __restrict__ A,
                                                   const uint16_t* __restrict__ Bt,
                                                   float* __restrict__ C) {
    extern __shared__ __align__(16) char smem2[];
    uint16_t* lds = (uint16_t*)smem2;
    const int Kd = 4096, Nn = 4096;
    const int t = threadIdx.x, wid = t >> 6, lane = t & 63;
    const int l16 = lane & 15, quad = lane >> 4;
    const int wr = wid >> 1, wc = wid & 1;
    const int bm0 = blockIdx.y * 256, bn0 = blockIdx.x * 128;

    f32x4 acc[4][4];
    const f32x4 z4 = {0.f, 0.f, 0.f, 0.f};
#pragma unroll
    for (int i = 0; i < 4; ++i)
#pragma unroll
        for (int j = 0; j < 4; ++j) acc[i][j] = z4;

    const int r0 = wid * 16 + (lane >> 2), c4 = lane & 3;
    const int sw2 = (r0 >> 1) & 3, sw7 = r0 & 7;
    const int offK0 = ((c4 ^ sw2) ^ sw7) * 8;
    const int offK1 = ((4 + (c4 ^ sw2)) ^ sw7) * 8;
    const uint16_t* pA0 = A + (size_t)(bm0 + r0) * Kd;
    const uint16_t* pA1 = pA0 + (size_t)128 * Kd;
    const uint16_t* pB0 = Bt + (size_t)(bn0 + r0) * Kd;
    uint16_t* stA = lds + wid * 512;
    uint16_t* stB = lds + 49152 + wid * 512;

    const int sA = (l16 >> 1) & 3;
    const int rdA = (wr * 64 + l16) * 32 + ((quad ^ sA) << 3);
    const int rdB = 49152 + (wc * 64 + l16) * 32 + ((quad ^ sA) << 3);

    bf16x8 afA[4], afB[4], bfA[4], bfB[4];

#define G2_STAGE(SLAB, OFF, TT) do { \
    gload_lds16(pA0 + (size_t)(TT) * 64 + (OFF), stA + (SLAB) * 8192); \
    gload_lds16(pA1 + (size_t)(TT) * 64 + (OFF), stA + (SLAB) * 8192 + 4096); \
    gload_lds16(pB0 + (size_t)(TT) * 64 + (OFF), stB + (SLAB) * 4096); } while (0)
#define G2_RD(AD, BD, CS) do { _Pragma("unroll") \
    for (int i_ = 0; i_ < 4; ++i_) \
        AD[i_] = *(const bf16x8*)&lds[(CS) * 8192 + rdA + i_ * 512]; \
    _Pragma("unroll") for (int j_ = 0; j_ < 4; ++j_) \
        BD[j_] = *(const bf16x8*)&lds[(CS) * 4096 + rdB + j_ * 512]; } while (0)
#define G2_MFMA(AF, BF) do { __builtin_amdgcn_s_setprio(1); \
    _Pragma("unroll") for (int i_ = 0; i_ < 4; ++i_) \
        _Pragma("unroll") for (int j_ = 0; j_ < 4; ++j_) \
            acc[i_][j_] = __builtin_amdgcn_mfma_f32_16x16x32_bf16(AF[i_], BF[j_], acc[i_][j_], 0, 0, 0); \
    __builtin_amdgcn_s_setprio(0); } while (0)

#define G2_PH(RA, RB, CSN, SST, OFF, TT, MA, MB) do { \
    G2_RD(RA, RB, CSN); \
    WAIT_VM(3); \
    G2_STAGE(SST, OFF, TT); \
    SCHED0; G2_MFMA(MA, MB); PH_BAR; } while (0)

    G2_STAGE(0, offK0, 0);
    G2_STAGE(1, offK1, 0);
    G2_STAGE(2, offK0, 1);
    G2_STAGE(3, offK1, 1);
    WAIT_VM(6);
    PH_BAR;
    G2_RD(afA, bfA, 0);

#pragma unroll 1
    for (int m = 0; m < 20; ++m) {
        G2_PH(afB, bfB, 1, 4, offK0, 3*m + 2, afA, bfA);
        G2_PH(afA, bfA, 2, 5, offK1, 3*m + 2, afB, bfB);
        G2_PH(afB, bfB, 3, 0, offK0, 3*m + 3, afA, bfA);
        G2_PH(afA, bfA, 4, 1, offK1, 3*m + 3, afB, bfB);
        G2_PH(afB, bfB, 5, 2, offK0, 3*m + 4, afA, bfA);
        G2_PH(afA, bfA, 0, 3, offK1, 3*m + 4, afB, bfB);
    }
    G2_PH(afB, bfB, 1, 4, offK0, 62, afA, bfA);
    G2_PH(afA, bfA, 2, 5, offK1, 62, afB, bfB);
    G2_PH(afB, bfB, 3, 0, offK0, 63, afA, bfA);
    G2_PH(afA, bfA, 4, 1, offK1, 63, afB, bfB);
    G2_RD(afB, bfB, 5); WAIT_VM(3); SCHED0; G2_MFMA(afA, bfA); PH_BAR;
    G2_RD(afA, bfA, 0); WAIT_VM(0); SCHED0; G2_MFMA(afB, bfB); PH_BAR;
    G2_RD(afB, bfB, 1);              SCHED0; G2_MFMA(afA, bfA); PH_BAR;
    SCHED0; G2_MFMA(afB, bfB);

#undef G2_PH
#undef G2_MFMA
#undef G2_RD
#undef G2_STAGE

#pragma unroll
    for (int i = 0; i < 4; ++i)
#pragma unroll
        for (int j = 0; j < 4; ++j) {
            int row = bm0 + wr * 64 + i * 16 + quad * 4;
            int col = bn0 + wc * 64 + j * 16 + l16;
            float* cp = C + (size_t)row * Nn + col;
            cp[0]              = acc[i][j][0];
            cp[(size_t)Nn]     = acc[i][j][1];
            cp[2 * (size_t)Nn] = acc[i][j][2];
            cp[3 * (size_t)Nn] = acc[i][j][3];
        }
}

// ============================================================================
// Flash attention, causal, GQA. 8 waves x 32 q-rows (two 16-row sets per wave
// sharing each K/V B-fragment read). Waves 0-3: rows [128p,128p+128), nk=p+1;
// waves 4-7: rows [128(15-p),128(16-p)), nk=16-p. Per-block cost constant.
// LDS 131072 B: sK [128][128] | sV [128][128] | sP 8 waves x [32][128].
// ============================================================================
__global__ __launch_bounds__(512, 2) void k_attn(const uint16_t* __restrict__ Q,
                                                 const uint16_t* __restrict__ K,
                                                 const uint16_t* __restrict__ Vt,
                                                 uint16_t* __restrict__ att) {
    extern __shared__ __align__(16) char asmem[];
    uint16_t* sK = (uint16_t*)asmem;            // 16384 elems
    uint16_t* sV = sK + 16384;                  // 16384 elems
    uint16_t* sP = sK + 32768;                  // 32768 elems
    const int p = blockIdx.x, n = blockIdx.y, kk = n >> 2;
    const int t = threadIdx.x, wid = t >> 6, lane = t & 63;
    const int l16 = lane & 15, quad = lane >> 4;
    const int grp = wid >> 2, wsub = wid & 3;
    const int nk_a = p + 1, nk_b = 16 - p;
    const int nk_w = grp ? nk_b : nk_a;
    const int qbase = (grp ? (15 - p) * 128 : p * 128) + wsub * 32;
    const f32x4 z4 = {0.f, 0.f, 0.f, 0.f};

    const uint16_t* Kbase = K  + ((size_t)kk * 2048 + wid * 16 + (lane >> 4)) * 128 + (lane & 15) * 8;
    const uint16_t* Vbase = Vt + ((size_t)kk * 128  + wid * 16 + (lane >> 4)) * 2048 + (lane & 15) * 8;
    uint16_t* sPw = sP + wid * 32 * 128;

    bf16x8 qf0[4], qf1[4];
#pragma unroll
    for (int kc = 0; kc < 4; ++kc) {
        qf0[kc] = *(const bf16x8*)(Q + (size_t)(n * 2048 + qbase + l16) * 128 + kc * 32 + quad * 8);
        qf1[kc] = *(const bf16x8*)(Q + (size_t)(n * 2048 + qbase + 16 + l16) * 128 + kc * 32 + quad * 8);
    }

    f32x4 O0[8], O1[8];
#pragma unroll
    for (int h = 0; h < 8; ++h) { O0[h] = z4; O1[h] = z4; }
    float mrow0[4], lrow0[4], mrow1[4], lrow1[4];
#pragma unroll
    for (int r = 0; r < 4; ++r) {
        mrow0[r] = -INFINITY; lrow0[r] = 0.f;
        mrow1[r] = -INFINITY; lrow1[r] = 0.f;
    }

    // softmax for one 16-row set: in-place exp on S, running m/l, rescale O
#define SM_SET(S, MR, LR, OO, ROWB, MASKED, S0V) do { \
    if (MASKED) { \
        _Pragma("unroll") for (int jn_ = 0; jn_ < 8; ++jn_) { \
            int sc_ = (S0V) + jn_ * 16 + l16; \
            _Pragma("unroll") for (int r_ = 0; r_ < 4; ++r_) { \
                int mr_ = (ROWB) + quad * 4 + r_; \
                if (sc_ > mr_) S[jn_][r_] = -INFINITY; \
            } \
        } \
    } \
    float alpha_[4]; \
    _Pragma("unroll") for (int r_ = 0; r_ < 4; ++r_) { \
        float mx_ = S[0][r_]; \
        _Pragma("unroll") for (int jn_ = 1; jn_ < 8; ++jn_) mx_ = fmaxf(mx_, S[jn_][r_]); \
        mx_ = fmaxf(mx_, __shfl_xor(mx_, 1)); \
        mx_ = fmaxf(mx_, __shfl_xor(mx_, 2)); \
        mx_ = fmaxf(mx_, __shfl_xor(mx_, 4)); \
        mx_ = fmaxf(mx_, __shfl_xor(mx_, 8)); \
        float mn_ = fmaxf(MR[r_], mx_); \
        float a_ = __expf(MR[r_] - mn_); \
        MR[r_] = mn_; \
        float sum_ = 0.f; \
        _Pragma("unroll") for (int jn_ = 0; jn_ < 8; ++jn_) { \
            float e_ = __expf(S[jn_][r_] - mn_); \
            S[jn_][r_] = e_; \
            sum_ += e_; \
        } \
        sum_ += __shfl_xor(sum_, 1); \
        sum_ += __shfl_xor(sum_, 2); \
        sum_ += __shfl_xor(sum_, 4); \
        sum_ += __shfl_xor(sum_, 8); \
        LR[r_] = LR[r_] * a_ + sum_; \
        alpha_[r_] = a_; \
    } \
    _Pragma("unroll") for (int h_ = 0; h_ < 8; ++h_) \
        _Pragma("unroll") for (int r_ = 0; r_ < 4; ++r_) OO[h_][r_] *= alpha_[r_]; \
} while (0)

    for (int st = 0; st < nk_b; ++st) {
        const int s0 = st * 128;
        __syncthreads();                       // prev tile's sK/sV reads done
#pragma unroll
        for (int j = 0; j < 4; ++j) {
            gload_lds16(Kbase + (size_t)(s0 + j * 4) * 128, &sK[(wid * 16 + j * 4) * 128]);
            gload_lds16(Vbase + (size_t)(j * 4) * 2048 + s0, &sV[(wid * 16 + j * 4) * 128]);
        }
        __syncthreads();                       // staged tile visible

        if (st < nk_w) {
            f32x4 S0[8], S1[8];
#pragma unroll
            for (int jn = 0; jn < 8; ++jn) { S0[jn] = z4; S1[jn] = z4; }
#pragma unroll
            for (int jn = 0; jn < 8; ++jn) {
                int krow = jn * 16 + l16;
#pragma unroll
                for (int kc = 0; kc < 4; ++kc) {
                    bf16x8 b = *(const bf16x8*)&sK[krow * 128 + (((kc * 4 + quad) ^ l16) << 3)];
                    S0[jn] = __builtin_amdgcn_mfma_f32_16x16x32_bf16(qf0[kc], b, S0[jn], 0, 0, 0);
                    S1[jn] = __builtin_amdgcn_mfma_f32_16x16x32_bf16(qf1[kc], b, S1[jn], 0, 0, 0);
                }
            }
            const int masked = (st == nk_w - 1);
            SM_SET(S0, mrow0, lrow0, O0, qbase, masked, s0);
            SM_SET(S1, mrow1, lrow1, O1, qbase + 16, masked, s0);

            // P-writes (both sets) into wave-private sP region, swizzled
#pragma unroll
            for (int jn = 0; jn < 8; ++jn)
#pragma unroll
                for (int r = 0; r < 4; ++r) {
                    int prow = quad * 4 + r;
                    int pcol = jn * 16 + l16;
                    int off = (pcol & 7) | ((((pcol >> 3) ^ prow) & 15) << 3);
                    sPw[prow * 128 + off]        = f2bf(S0[jn][r]);
                    sPw[(16 + prow) * 128 + off] = f2bf(S1[jn][r]);
                }
            bf16x8 pf0[4], pf1[4];
#pragma unroll
            for (int ksv = 0; ksv < 4; ++ksv) {
                pf0[ksv] = *(const bf16x8*)&sPw[l16 * 128 + (((ksv * 4 + quad) ^ l16) << 3)];
                pf1[ksv] = *(const bf16x8*)&sPw[(16 + l16) * 128 + (((ksv * 4 + quad) ^ l16) << 3)];
            }
#pragma unroll
            for (int hj = 0; hj < 8; ++hj) {
                int vrow = hj * 16 + l16;
#pragma unroll
                for (int ksv = 0; ksv < 4; ++ksv) {
                    bf16x8 b = *(const bf16x8*)&sV[vrow * 128 + (((ksv * 4 + quad) ^ l16) << 3)];
                    O0[hj] = __builtin_amdgcn_mfma_f32_16x16x32_bf16(pf0[ksv], b, O0[hj], 0, 0, 0);
                    O1[hj] = __builtin_amdgcn_mfma_f32_16x16x32_bf16(pf1[ksv], b, O1[hj], 0, 0, 0);
                }
            }
        }
    }
#undef SM_SET

    // epilogue per set: normalize, wave-local LDS round-trip, swizzled stores
#pragma unroll
    for (int set = 0; set < 2; ++set) {
        float inv[4];
#pragma unroll
        for (int r = 0; r < 4; ++r)
            inv[r] = 1.0f / (set ? lrow1[r] : lrow0[r]);
#pragma unroll
        for (int hj = 0; hj < 8; ++hj)
#pragma unroll
            for (int r = 0; r < 4; ++r) {
                float v = (set ? O1[hj][r] : O0[hj][r]) * inv[r];
                sPw[(quad * 4 + r) * 132 + hj * 16 + l16] = f2bf(v);
            }
#pragma unroll
        for (int it = 0; it < 4; ++it) {
            int slot = it * 64 + lane, rloc = slot >> 4, cl = slot & 15;
            bf16x8 v = *(const bf16x8*)&sPw[rloc * 132 + cl * 8];
            int R = qbase + set * 16 + rloc;
            size_t dst = (size_t)R * 4096 + n * 128 + ((cl & 8) << 3) + (((cl & 7) ^ (R & 7)) << 3);
            *(uint4*)&att[dst] = *(uint4*)&v;
        }
    }
}

// ============================================================================
extern "C" void kernel_launch(void* const* d_in, const int* in_sizes, int n_in,
                              void* d_out, int out_size, void* d_ws, size_t ws_size,
                              hipStream_t stream) {
    const float* x   = (const float*)d_in[0];
    const int*   sp  = (const int*)d_in[1];
    const float* qw  = (const float*)d_in[3];
    const float* kvw = (const float*)d_in[4];
    const float* ow  = (const float*)d_in[5];
    const float* qsc = (const float*)d_in[6];
    const float* ksc = (const float*)d_in[7];
    float* out = (float*)d_out;

    char* ws = (char*)d_ws;
    uint16_t* xb   = (uint16_t*)(ws);
    uint16_t* Wt   = (uint16_t*)(ws + (size_t)(16u << 20));
    uint16_t* Qb   = (uint16_t*)(ws + (size_t)(64u << 20));
    uint16_t* Kb   = (uint16_t*)(ws + (size_t)(80u << 20));
    uint16_t* Vtb  = (uint16_t*)(ws + (size_t)(84u << 20));
    uint16_t* att  = (uint16_t*)(ws);                           // over dead xb
    uint16_t* Ot   = (uint16_t*)(ws + (size_t)(16u << 20));     // over dead Wt

    static bool attr_done = false;
    if (!attr_done) {
        hipFuncSetAttribute(reinterpret_cast<const void*>(k_gemm_qkv),
                            hipFuncAttributeMaxDynamicSharedMemorySize, 137216);
        hipFuncSetAttribute(reinterpret_cast<const void*>(k_gemm2p),
                            hipFuncAttributeMaxDynamicSharedMemorySize, 147456);
        hipFuncSetAttribute(reinterpret_cast<const void*>(k_attn),
                            hipFuncAttributeMaxDynamicSharedMemorySize, 131072);
        attr_done = true;
    }

    k_cvt_x    <<<4096, 256, 0, stream>>>(x, xb);
    k_prep_wt  <<<dim3(2, 64, 48), 256, 0, stream>>>(qw, kvw, Wt);
    k_gemm_qkv <<<dim3(24, 8), 512, 137216, stream>>>(xb, Wt, sp, qsc, ksc, Qb, Kb, Vtb);
    k_prep_ot  <<<dim3(64, 2, 32), 256, 0, stream>>>(ow, Ot);
    k_attn     <<<dim3(8, 32), 512, 131072, stream>>>(Qb, Kb, Vtb, att);
    k_gemm2p   <<<dim3(32, 8), 512, 147456, stream>>>(att, Ot, out);
}

// Round 6
// 509.615 us; speedup vs baseline: 1.0242x; 1.0242x over previous
//
#include <hip/hip_runtime.h>
#include <stdint.h>

// ============================================================================
// Attention_16441134809293 : B=1 T=2048 D=4096 N=32 KV=8 H=128, fp32 in/out.
// Round 9 (fix of round 8's data race):
//  - BUG FIX: round 8 fused prep_ot into k_gemm_qkv but kept Ot at ws+16MB,
//    overwriting the live Wt B-operand [16,64M) mid-GEMM. Now: if ws_size
//    >= 120MB, Ot lives at ws+88MB (disjoint from gemm1's working set) and
//    the fused path runs (grid 32x8; bx>=24 blocks transpose o_w on the 64
//    idle CUs). Else: round-7 fallback (separate k_prep_ot, Ot over dead Wt).
//  - k_prep: merged x->bf16 + Wt transpose (one launch).
//  - k_gemm2b: 128x128 tile, 4 waves, 64KB 4-slab LDS ring, 512 blocks =
//    2 blocks/CU (cross-block overlap hides barrier/drain, m114). vmcnt(8)
//    steady, tail 8->4->0. Same K order as before -> bit-identical.
//  - k_gemm_qkv K-loop & k_attn unchanged from rounds 6/7 (verified passing).
// Workspace map:
//   phase1 (gemm1): xb[0,16M) Wt[16,64M) Q[64,80M) K[80,84M) Vt[84,88M)
//                   Ot[88,120M) if ws allows (fused prep), else written later
//   phase2 (attn) : att[0,16M)  (over dead xb)
//   phase3 (gemm2): reads att + Ot
// ============================================================================

typedef __bf16 bf16x8 __attribute__((ext_vector_type(8)));
typedef float  f32x4  __attribute__((ext_vector_type(4)));

__device__ __forceinline__ uint16_t f2bf(float f) {
    union { float f; uint32_t u; } v; v.f = f;
    uint32_t r = v.u + 0x7fffu + ((v.u >> 16) & 1u);   // RNE
    return (uint16_t)(r >> 16);
}

__device__ __forceinline__ void gload_lds16(const void* g, void* l) {
    __builtin_amdgcn_global_load_lds(
        (const __attribute__((address_space(1))) uint32_t*)g,
        (__attribute__((address_space(3))) uint32_t*)l, 16, 0, 0);
}

// ---------------- fused: x -> bf16 swizzled (blocks 0..4095) and
//                  q_w/kv_w -> Wt (blocks 4096..10239)
__global__ __launch_bounds__(256) void k_prep(const float* __restrict__ x,
                                              uint16_t* __restrict__ xb,
                                              const float* __restrict__ qw,
                                              const float* __restrict__ kvw,
                                              uint16_t* __restrict__ Wt) {
    __shared__ uint16_t tile[64][65];
    const int b = blockIdx.x, t = threadIdx.x;
    if (b < 4096) {
        int i = (b * 256 + t) * 8;
        int r = i >> 12, k = i & 4095;
        float4 a = *(const float4*)(x + i);
        float4 c = *(const float4*)(x + i + 4);
        uint16_t tmp[8];
        tmp[0] = f2bf(a.x); tmp[1] = f2bf(a.y); tmp[2] = f2bf(a.z); tmp[3] = f2bf(a.w);
        tmp[4] = f2bf(c.x); tmp[5] = f2bf(c.y); tmp[6] = f2bf(c.z); tmp[7] = f2bf(c.w);
        int dst = r * 4096 + (k & ~63) + (((((k >> 3) & 7) ^ (r & 7))) << 3);
        *(uint4*)(xb + dst) = *(uint4*)tmp;
        return;
    }
    const int bid = b - 4096;
    const int m = bid >> 7, rem = bid & 127, dx = rem >> 1, hx = rem & 1;
    const float* src = (m < 32) ? (qw + (size_t)m * 524288)
                                : (kvw + (size_t)(m - 32) * 524288);
    const int d0 = dx * 64, h0 = hx * 64;
#pragma unroll
    for (int i = 0; i < 16; ++i) {
        int idx = i * 256 + t, r = idx >> 6, c = idx & 63;
        tile[r][c] = f2bf(src[(size_t)(d0 + r) * 128 + h0 + c]);
    }
    __syncthreads();
#pragma unroll
    for (int it = 0; it < 2; ++it) {
        int slot = it * 256 + t, hr = slot >> 3, cl = slot & 7;
        int R = m * 128 + h0 + hr;
        uint16_t tmp[8];
#pragma unroll
        for (int e = 0; e < 8; ++e) tmp[e] = tile[cl * 8 + e][hr];
        *(uint4*)&Wt[(size_t)R * 4096 + d0 + ((cl ^ (R & 7)) << 3)] = *(uint4*)tmp;
    }
}

// --------------------- o_w[n][h][d] -> Ot[d][n*128+h] bf16 (B^T), swizzled
// (fallback path when workspace is too small for the fused prep)
__global__ __launch_bounds__(256) void k_prep_ot(const float* __restrict__ ow,
                                                 uint16_t* __restrict__ Ot) {
    const int dx = blockIdx.x, hx = blockIdx.y, n = blockIdx.z;
    const float* src = ow + (size_t)n * 524288;                  // [128][4096]
    __shared__ uint16_t tile[64][65];                            // [h][d]
    const int t = threadIdx.x, h0 = hx * 64, d0 = dx * 64;
#pragma unroll
    for (int i = 0; i < 16; ++i) {
        int idx = i * 256 + t, r = idx >> 6, c = idx & 63;
        tile[r][c] = f2bf(src[(size_t)(h0 + r) * 4096 + d0 + c]);
    }
    __syncthreads();
#pragma unroll
    for (int it = 0; it < 2; ++it) {
        int slot = it * 256 + t, dr = slot >> 3, cl = slot & 7;
        int R = d0 + dr;
        uint16_t tmp[8];
#pragma unroll
        for (int e = 0; e < 8; ++e) tmp[e] = tile[cl * 8 + e][dr];
        *(uint4*)&Ot[(size_t)R * 4096 + n * 128 + h0 + ((cl ^ (R & 7)) << 3)] = *(uint4*)tmp;
    }
}

// ---------------------------------------------------------------- sync macros
#define PH_BAR do { asm volatile("" ::: "memory"); \
                    __builtin_amdgcn_s_barrier(); \
                    asm volatile("" ::: "memory"); } while (0)
#define WAIT_VM(N) do { asm volatile("s_waitcnt vmcnt(" #N ")" ::: "memory"); \
                        __builtin_amdgcn_sched_barrier(0); } while (0)
#define WAIT_LGKM do { asm volatile("s_waitcnt lgkmcnt(0)" ::: "memory"); \
                       __builtin_amdgcn_sched_barrier(0); } while (0)
#define SCHED0 __builtin_amdgcn_sched_barrier(0)

// ============================================================================
// gemm1 + fused RMSNorm/RoPE epilogue, 256x256 tile, 8 waves, pipelined
// (K-loop unchanged from round 6). In the fused path (grid 32x8), blocks
// bx>=24 transpose o_w -> Ot (at ws+88M, NO overlap with live buffers) on
// the 64 CUs the 192-block GEMM leaves idle. Fallback grid is 24x8 (branch
// never taken).
// ============================================================================
__global__ __launch_bounds__(512, 2) void k_gemm_qkv(const uint16_t* __restrict__ A,
                                                     const uint16_t* __restrict__ Bt,
                                                     const int* __restrict__ pos,
                                                     const float* __restrict__ qs,
                                                     const float* __restrict__ ks,
                                                     uint16_t* __restrict__ Qg,
                                                     uint16_t* __restrict__ Kg,
                                                     uint16_t* __restrict__ Vg,
                                                     const float* __restrict__ ow,
                                                     uint16_t* __restrict__ Ot) {
    extern __shared__ __align__(16) char smem[];
    const int t = threadIdx.x;
    const int bx = blockIdx.x;

    if (bx >= 24) {
        // ---- o_w[n][h][d] -> Ot[d][n*128+h] (B^T), swizzled; Ot disjoint ----
        uint16_t* tl = (uint16_t*)smem + (t >> 8) * 64 * 65;
        const int tt = t & 255;
        const int jb = ((bx - 24) * 8 + blockIdx.y) * 64;
        for (int it = 0; it < 32; ++it) {
            int job = jb + it * 2 + (t >> 8);
            int n2 = job & 31, hx = (job >> 5) & 1, dx = job >> 6;
            const float* src = ow + (size_t)n2 * 524288;   // [128][4096]
            const int h0 = hx * 64, d0 = dx * 64;
#pragma unroll
            for (int i = 0; i < 16; ++i) {
                int idx = i * 256 + tt, r = idx >> 6, c = idx & 63;
                tl[r * 65 + c] = f2bf(src[(size_t)(h0 + r) * 4096 + d0 + c]);
            }
            __syncthreads();
#pragma unroll
            for (int it2 = 0; it2 < 2; ++it2) {
                int slot = it2 * 256 + tt, dr = slot >> 3, cl = slot & 7;
                int R = d0 + dr;
                uint16_t tmp[8];
#pragma unroll
                for (int e = 0; e < 8; ++e) tmp[e] = tl[(cl * 8 + e) * 65 + dr];
                *(uint4*)&Ot[(size_t)R * 4096 + n2 * 128 + h0 + ((cl ^ (R & 7)) << 3)]
                    = *(uint4*)tmp;
            }
            __syncthreads();
        }
        return;
    }

    uint16_t* lds = (uint16_t*)smem;
    const int Kd = 4096;
    const int wid = t >> 6, lane = t & 63;
    const int l16 = lane & 15, quad = lane >> 4;
    const int wr = wid >> 2, wc = wid & 3;
    const int bm0 = blockIdx.y * 256, bn0 = bx * 256;

    f32x4 acc[8][4];
    const f32x4 z4 = {0.f, 0.f, 0.f, 0.f};
#pragma unroll
    for (int i = 0; i < 8; ++i)
#pragma unroll
        for (int j = 0; j < 4; ++j) acc[i][j] = z4;

    const int r0 = wid * 16 + (lane >> 2), c4 = lane & 3;
    const int sw2 = (r0 >> 1) & 3, sw7 = r0 & 7;
    const int offK0 = (((c4 ^ sw2)) ^ sw7) * 8;
    const int offK1 = ((4 + (c4 ^ sw2)) ^ sw7) * 8;
    const uint16_t* pA0 = A + (size_t)(bm0 + r0) * Kd;
    const uint16_t* pA1 = pA0 + (size_t)128 * Kd;
    const uint16_t* pB0 = Bt + (size_t)(bn0 + r0) * Kd;
    const uint16_t* pB1 = pB0 + (size_t)128 * Kd;
    uint16_t* stA = lds + wid * 512;
    uint16_t* stB = lds + 32768 + wid * 512;

    const int sA = (l16 >> 1) & 3;
    const int rdA = (wr * 128 + l16) * 32 + ((quad ^ sA) << 3);
    const int rdB = 32768 + (wc * 64 + l16) * 32 + ((quad ^ sA) << 3);

    bf16x8 afA[4], afB[4], bfA[4], bfB[4];

#define STAGE_A(SLAB, OFF, TT) do { \
    gload_lds16(pA0 + (size_t)(TT) * 64 + (OFF), stA + (SLAB) * 8192); \
    gload_lds16(pA1 + (size_t)(TT) * 64 + (OFF), stA + (SLAB) * 8192 + 4096); } while (0)
#define STAGE_B(SLAB, OFF, TT) do { \
    gload_lds16(pB0 + (size_t)(TT) * 64 + (OFF), stB + (SLAB) * 8192); \
    gload_lds16(pB1 + (size_t)(TT) * 64 + (OFF), stB + (SLAB) * 8192 + 4096); } while (0)
#define RD_A(DST, SLAB, I0) do { _Pragma("unroll") \
    for (int i_ = 0; i_ < 4; ++i_) \
        DST[i_] = *(const bf16x8*)&lds[(SLAB) * 8192 + rdA + ((I0) + i_) * 512]; } while (0)
#define RD_B(DST, SLAB) do { _Pragma("unroll") \
    for (int j_ = 0; j_ < 4; ++j_) \
        DST[j_] = *(const bf16x8*)&lds[(SLAB) * 8192 + rdB + j_ * 512]; } while (0)
#define MFMA16(AF, BF, I0) do { __builtin_amdgcn_s_setprio(1); \
    _Pragma("unroll") for (int i_ = 0; i_ < 4; ++i_) \
        _Pragma("unroll") for (int j_ = 0; j_ < 4; ++j_) \
            acc[(I0) + i_][j_] = __builtin_amdgcn_mfma_f32_16x16x32_bf16(AF[i_], BF[j_], acc[(I0) + i_][j_], 0, 0, 0); \
    __builtin_amdgcn_s_setprio(0); } while (0)

#define TILE(TT, BUF) do { \
    RD_A(afB, 2*(BUF), 4); \
    WAIT_VM(4); \
    STAGE_A(2*((BUF)^1)+1, offK1, (TT)+1); \
    SCHED0; MFMA16(afA, bfA, 0); PH_BAR; \
    RD_A(afA, 2*(BUF)+1, 0); RD_B(bfB, 2*(BUF)+1); \
    STAGE_B(2*((BUF)^1)+1, offK1, (TT)+1); \
    SCHED0; MFMA16(afB, bfA, 4); PH_BAR; \
    RD_A(afB, 2*(BUF)+1, 4); \
    WAIT_VM(4); \
    STAGE_A(2*(BUF), offK0, (TT)+2); \
    SCHED0; MFMA16(afA, bfB, 0); PH_BAR; \
    RD_A(afA, 2*((BUF)^1), 0); RD_B(bfA, 2*((BUF)^1)); \
    STAGE_B(2*(BUF), offK0, (TT)+2); \
    SCHED0; MFMA16(afB, bfB, 4); PH_BAR; \
} while (0)

    STAGE_A(0, offK0, 0); STAGE_B(0, offK0, 0);
    STAGE_A(1, offK1, 0); STAGE_B(1, offK1, 0);
    STAGE_A(2, offK0, 1); STAGE_B(2, offK0, 1);
    WAIT_VM(8);
    PH_BAR;
    RD_A(afA, 0, 0); RD_B(bfA, 0);

#pragma unroll 1
    for (int Ti = 0; Ti < 31; ++Ti) {
        TILE(2 * Ti, 0);
        TILE(2 * Ti + 1, 1);
    }

    RD_A(afB, 0, 4); WAIT_VM(4); STAGE_A(3, offK1, 63);
    SCHED0; MFMA16(afA, bfA, 0); PH_BAR;
    RD_A(afA, 1, 0); RD_B(bfB, 1); STAGE_B(3, offK1, 63);
    SCHED0; MFMA16(afB, bfA, 4); PH_BAR;
    RD_A(afB, 1, 4); WAIT_VM(4);
    SCHED0; MFMA16(afA, bfB, 0); PH_BAR;
    RD_A(afA, 2, 0); RD_B(bfA, 2);
    SCHED0; MFMA16(afB, bfB, 4); PH_BAR;
    RD_A(afB, 2, 4); WAIT_VM(0);
    SCHED0; MFMA16(afA, bfA, 0); PH_BAR;
    RD_A(afA, 3, 0); RD_B(bfB, 3);
    SCHED0; MFMA16(afB, bfA, 4); PH_BAR;
    RD_A(afB, 3, 4);
    SCHED0; MFMA16(afA, bfB, 0); PH_BAR;
    SCHED0; MFMA16(afB, bfB, 4);

#undef TILE
#undef MFMA16
#undef RD_B
#undef RD_A
#undef STAGE_B
#undef STAGE_A

    // ---------------- fused epilogue: RMSNorm + RoPE + store ----------------
    float* X   = (float*)smem;                 // [128][260] fp32
    float* ssq = (float*)(smem + 133120);      // [256 rows][2 heads][2 partials]

#pragma unroll
    for (int i = 0; i < 8; ++i)
#pragma unroll
        for (int r = 0; r < 4; ++r) {
            float s = 0.f;
#pragma unroll
            for (int j = 0; j < 4; ++j) s += acc[i][j][r] * acc[i][j][r];
            s += __shfl_xor(s, 1); s += __shfl_xor(s, 2);
            s += __shfl_xor(s, 4); s += __shfl_xor(s, 8);
            if (l16 == 0)
                ssq[(wr * 128 + i * 16 + quad * 4 + r) * 4 + (wc >> 1) * 2 + (wc & 1)] = s;
        }
    __syncthreads();

    const int cat = (bx < 16) ? 0 : (bx < 20 ? 1 : 2);
    float s1 = 0.f, s2 = 0.f, invts = 0.f;
    if (cat < 2) {
        const float* sc = cat ? ks : qs;
        s1 = 1.0f + sc[lane];
        s2 = 1.0f + sc[lane + 64];
        invts = exp2f((float)lane * -0.20762050593046014f);
    }

#pragma unroll
    for (int pass = 0; pass < 2; ++pass) {
        if (wr == pass) {
#pragma unroll
            for (int i = 0; i < 8; ++i)
#pragma unroll
                for (int j = 0; j < 4; ++j)
#pragma unroll
                    for (int r = 0; r < 4; ++r)
                        X[(i * 16 + quad * 4 + r) * 260 + wc * 64 + j * 16 + l16] = acc[i][j][r];
        }
        __syncthreads();
        for (int rr = 0; rr < 16; ++rr) {
            const int lrow = wid * 16 + rr;
            const int grow = bm0 + pass * 128 + lrow;
            float sn = 0.f, cs = 0.f;
            if (cat < 2) {
                float ang = (float)pos[grow] * invts;
                __sincosf(ang, &sn, &cs);
            }
#pragma unroll
            for (int hh = 0; hh < 2; ++hh) {
                const int sb = (pass * 128 + lrow) * 4 + hh * 2;
                float rn = rsqrtf((ssq[sb] + ssq[sb + 1]) * 0.0078125f + 1e-6f);
                float x1 = X[lrow * 260 + hh * 128 + lane];
                float x2 = X[lrow * 260 + hh * 128 + 64 + lane];
                if (cat < 2) {
                    float y1 = x1 * rn * s1, y2 = x2 * rn * s2;
                    X[lrow * 260 + hh * 128 + lane]      = y1 * cs - y2 * sn;
                    X[lrow * 260 + hh * 128 + 64 + lane] = y2 * cs + y1 * sn;
                } else {
                    X[lrow * 260 + hh * 128 + lane]      = x1 * rn;
                    X[lrow * 260 + hh * 128 + 64 + lane] = x2 * rn;
                }
            }
        }
        __syncthreads();
        if (cat == 2) {
#pragma unroll
            for (int it = 0; it < 8; ++it) {
                int slot = it * 512 + t, hh = slot >> 11, rem = slot & 2047;
                int h = rem >> 4, sc2 = rem & 15;
                uint16_t tmp[8];
#pragma unroll
                for (int e = 0; e < 8; ++e)
                    tmp[e] = f2bf(X[(sc2 * 8 + e) * 260 + hh * 128 + h]);
                int n = bx * 2 + hh;
                *(uint4*)&Vg[((size_t)(n - 40) * 128 + h) * 2048 + (bm0 + pass * 128)
                             + ((sc2 ^ (h & 15)) << 3)] = *(uint4*)tmp;
            }
        } else {
#pragma unroll
            for (int it = 0; it < 8; ++it) {
                int slot = it * 512 + t, hh = slot >> 11, rem = slot & 2047;
                int lrow = rem >> 4, c = rem & 15;
                int tg = bm0 + pass * 128 + lrow, n = bx * 2 + hh;
                f32x4 a = *(f32x4*)&X[lrow * 260 + hh * 128 + c * 8];
                f32x4 b = *(f32x4*)&X[lrow * 260 + hh * 128 + c * 8 + 4];
                uint16_t tmp[8];
#pragma unroll
                for (int e = 0; e < 4; ++e) { tmp[e] = f2bf(a[e]); tmp[4 + e] = f2bf(b[e]); }
                if (cat == 0)
                    *(uint4*)&Qg[((size_t)n * 2048 + tg) * 128 + c * 8] = *(uint4*)tmp;
                else
                    *(uint4*)&Kg[((size_t)(n - 32) * 2048 + tg) * 128
                                 + ((c ^ (tg & 15)) << 3)] = *(uint4*)tmp;
            }
        }
        __syncthreads();
    }
}

// ============================================================================
// gemm2: out = att(2048x4096) * Ot^T(4096x4096), 128x128 tile, 4 waves,
// grid 32x16 = 512 blocks = 2 blocks/CU. LDS 65536 B: A 4 slabs x [128][32]
// + B 4 slabs x [128][32]. Phase p: [RD slab p%4 (8 b128); STAGE slab
// (p+3)%4 (4 gloads, data for phase p+3); vmcnt(8) (confirms phase p+1 slab);
// BAR; lgkm0; 16 MFMA; BAR]. Cross-block overlap hides the drains.
// ============================================================================
__global__ __launch_bounds__(256, 2) void k_gemm2b(const uint16_t* __restrict__ A,
                                                   const uint16_t* __restrict__ Bt,
                                                   float* __restrict__ C) {
    extern __shared__ __align__(16) char smem2[];
    uint16_t* lds = (uint16_t*)smem2;
    const int Kd = 4096, Nn = 4096;
    const int t = threadIdx.x, wid = t >> 6, lane = t & 63;
    const int l16 = lane & 15, quad = lane >> 4;
    const int wr = wid >> 1, wc = wid & 1;
    const int bm0 = blockIdx.y * 128, bn0 = blockIdx.x * 128;

    f32x4 acc[4][4];
    const f32x4 z4 = {0.f, 0.f, 0.f, 0.f};
#pragma unroll
    for (int i = 0; i < 4; ++i)
#pragma unroll
        for (int j = 0; j < 4; ++j) acc[i][j] = z4;

    const int r0 = wid * 32 + (lane >> 2), c4 = lane & 3;
    const int sw2 = (r0 >> 1) & 3, sw7 = r0 & 7;
    const int offK0 = ((c4 ^ sw2) ^ sw7) * 8;
    const int offK1 = ((4 + (c4 ^ sw2)) ^ sw7) * 8;
    const uint16_t* pA0 = A + (size_t)(bm0 + r0) * Kd;
    const uint16_t* pA1 = pA0 + (size_t)16 * Kd;
    const uint16_t* pB0 = Bt + (size_t)(bn0 + r0) * Kd;
    const uint16_t* pB1 = pB0 + (size_t)16 * Kd;
    uint16_t* stA = lds + wid * 1024;
    uint16_t* stB = lds + 16384 + wid * 1024;

    const int sA = (l16 >> 1) & 3;
    const int rdA = (wr * 64 + l16) * 32 + ((quad ^ sA) << 3);
    const int rdB = (wc * 64 + l16) * 32 + ((quad ^ sA) << 3);

    bf16x8 af[4], bf[4];

#define B2_STAGE(SLAB, OFF, TT) do { \
    gload_lds16(pA0 + (size_t)(TT) * 64 + (OFF), stA + (SLAB) * 4096); \
    gload_lds16(pA1 + (size_t)(TT) * 64 + (OFF), stA + (SLAB) * 4096 + 512); \
    gload_lds16(pB0 + (size_t)(TT) * 64 + (OFF), stB + (SLAB) * 4096); \
    gload_lds16(pB1 + (size_t)(TT) * 64 + (OFF), stB + (SLAB) * 4096 + 512); } while (0)
#define B2_RD(CS) do { _Pragma("unroll") \
    for (int i_ = 0; i_ < 4; ++i_) \
        af[i_] = *(const bf16x8*)&lds[(CS) * 4096 + rdA + i_ * 512]; \
    _Pragma("unroll") for (int j_ = 0; j_ < 4; ++j_) \
        bf[j_] = *(const bf16x8*)&lds[16384 + (CS) * 4096 + rdB + j_ * 512]; } while (0)
#define B2_MFMA do { __builtin_amdgcn_s_setprio(1); \
    _Pragma("unroll") for (int i_ = 0; i_ < 4; ++i_) \
        _Pragma("unroll") for (int j_ = 0; j_ < 4; ++j_) \
            acc[i_][j_] = __builtin_amdgcn_mfma_f32_16x16x32_bf16(af[i_], bf[j_], acc[i_][j_], 0, 0, 0); \
    __builtin_amdgcn_s_setprio(0); } while (0)
#define B2_PH(CS, SG, OFF, TT) do { \
    B2_RD(CS); \
    B2_STAGE(SG, OFF, TT); \
    WAIT_VM(8); \
    PH_BAR; WAIT_LGKM; \
    B2_MFMA; PH_BAR; } while (0)

    // prologue: stage phases 0,1,2 (slabs 0,1,2); confirm slab 0
    B2_STAGE(0, offK0, 0);
    B2_STAGE(1, offK1, 0);
    B2_STAGE(2, offK0, 1);
    WAIT_VM(8);
    PH_BAR;

    // phases 0..123 (stage for phases 3..126)
#pragma unroll 1
    for (int m = 0; m < 31; ++m) {
        B2_PH(0, 3, offK1, 2 * m + 1);
        B2_PH(1, 0, offK0, 2 * m + 2);
        B2_PH(2, 1, offK1, 2 * m + 2);
        B2_PH(3, 2, offK0, 2 * m + 3);
    }
    // phase 124 (stage for phase 127)
    B2_PH(0, 3, offK1, 63);
    // phases 125..127: drain 8 -> 4 -> 0
    B2_RD(1); WAIT_VM(4); PH_BAR; WAIT_LGKM; B2_MFMA; PH_BAR;
    B2_RD(2); WAIT_VM(0); PH_BAR; WAIT_LGKM; B2_MFMA; PH_BAR;
    B2_RD(3);             PH_BAR; WAIT_LGKM; B2_MFMA;

#undef B2_PH
#undef B2_MFMA
#undef B2_RD
#undef B2_STAGE

#pragma unroll
    for (int i = 0; i < 4; ++i)
#pragma unroll
        for (int j = 0; j < 4; ++j) {
            int row = bm0 + wr * 64 + i * 16 + quad * 4;
            int col = bn0 + wc * 64 + j * 16 + l16;
            float* cp = C + (size_t)row * Nn + col;
            cp[0]              = acc[i][j][0];
            cp[(size_t)Nn]     = acc[i][j][1];
            cp[2 * (size_t)Nn] = acc[i][j][2];
            cp[3 * (size_t)Nn] = acc[i][j][3];
        }
}

// ============================================================================
// Flash attention, causal, GQA (unchanged from round 7). 8 waves x 32 q-rows.
// ============================================================================
__global__ __launch_bounds__(512, 2) void k_attn(const uint16_t* __restrict__ Q,
                                                 const uint16_t* __restrict__ K,
                                                 const uint16_t* __restrict__ Vt,
                                                 uint16_t* __restrict__ att) {
    extern __shared__ __align__(16) char asmem[];
    uint16_t* sK = (uint16_t*)asmem;
    uint16_t* sV = sK + 16384;
    uint16_t* sP = sK + 32768;
    const int p = blockIdx.x, n = blockIdx.y, kk = n >> 2;
    const int t = threadIdx.x, wid = t >> 6, lane = t & 63;
    const int l16 = lane & 15, quad = lane >> 4;
    const int grp = wid >> 2, wsub = wid & 3;
    const int nk_b = 16 - p;
    const int nk_w = grp ? nk_b : (p + 1);
    const int qbase = (grp ? (15 - p) * 128 : p * 128) + wsub * 32;
    const f32x4 z4 = {0.f, 0.f, 0.f, 0.f};

    const uint16_t* Kbase = K  + ((size_t)kk * 2048 + wid * 16 + (lane >> 4)) * 128 + (lane & 15) * 8;
    const uint16_t* Vbase = Vt + ((size_t)kk * 128  + wid * 16 + (lane >> 4)) * 2048 + (lane & 15) * 8;
    uint16_t* sPw = sP + wid * 32 * 128;

    bf16x8 qf0[4], qf1[4];
#pragma unroll
    for (int kc = 0; kc < 4; ++kc) {
        qf0[kc] = *(const bf16x8*)(Q + (size_t)(n * 2048 + qbase + l16) * 128 + kc * 32 + quad * 8);
        qf1[kc] = *(const bf16x8*)(Q + (size_t)(n * 2048 + qbase + 16 + l16) * 128 + kc * 32 + quad * 8);
    }

    f32x4 O0[8], O1[8];
#pragma unroll
    for (int h = 0; h < 8; ++h) { O0[h] = z4; O1[h] = z4; }
    float mrow0[4], lrow0[4], mrow1[4], lrow1[4];
#pragma unroll
    for (int r = 0; r < 4; ++r) {
        mrow0[r] = -INFINITY; lrow0[r] = 0.f;
        mrow1[r] = -INFINITY; lrow1[r] = 0.f;
    }

#define SM_SET(S, MR, LR, OO, ROWB, MASKED, S0V) do { \
    if (MASKED) { \
        _Pragma("unroll") for (int jn_ = 0; jn_ < 8; ++jn_) { \
            int sc_ = (S0V) + jn_ * 16 + l16; \
            _Pragma("unroll") for (int r_ = 0; r_ < 4; ++r_) { \
                int mr_ = (ROWB) + quad * 4 + r_; \
                if (sc_ > mr_) S[jn_][r_] = -INFINITY; \
            } \
        } \
    } \
    float alpha_[4]; \
    _Pragma("unroll") for (int r_ = 0; r_ < 4; ++r_) { \
        float mx_ = S[0][r_]; \
        _Pragma("unroll") for (int jn_ = 1; jn_ < 8; ++jn_) mx_ = fmaxf(mx_, S[jn_][r_]); \
        mx_ = fmaxf(mx_, __shfl_xor(mx_, 1)); \
        mx_ = fmaxf(mx_, __shfl_xor(mx_, 2)); \
        mx_ = fmaxf(mx_, __shfl_xor(mx_, 4)); \
        mx_ = fmaxf(mx_, __shfl_xor(mx_, 8)); \
        float mn_ = fmaxf(MR[r_], mx_); \
        float a_ = __expf(MR[r_] - mn_); \
        MR[r_] = mn_; \
        float sum_ = 0.f; \
        _Pragma("unroll") for (int jn_ = 0; jn_ < 8; ++jn_) { \
            float e_ = __expf(S[jn_][r_] - mn_); \
            S[jn_][r_] = e_; \
            sum_ += e_; \
        } \
        sum_ += __shfl_xor(sum_, 1); \
        sum_ += __shfl_xor(sum_, 2); \
        sum_ += __shfl_xor(sum_, 4); \
        sum_ += __shfl_xor(sum_, 8); \
        LR[r_] = LR[r_] * a_ + sum_; \
        alpha_[r_] = a_; \
    } \
    _Pragma("unroll") for (int h_ = 0; h_ < 8; ++h_) \
        _Pragma("unroll") for (int r_ = 0; r_ < 4; ++r_) OO[h_][r_] *= alpha_[r_]; \
} while (0)

    for (int st = 0; st < nk_b; ++st) {
        const int s0 = st * 128;
        __syncthreads();
#pragma unroll
        for (int j = 0; j < 4; ++j) {
            gload_lds16(Kbase + (size_t)(s0 + j * 4) * 128, &sK[(wid * 16 + j * 4) * 128]);
            gload_lds16(Vbase + (size_t)(j * 4) * 2048 + s0, &sV[(wid * 16 + j * 4) * 128]);
        }
        __syncthreads();

        if (st < nk_w) {
            f32x4 S0[8], S1[8];
#pragma unroll
            for (int jn = 0; jn < 8; ++jn) { S0[jn] = z4; S1[jn] = z4; }
#pragma unroll
            for (int jn = 0; jn < 8; ++jn) {
                int krow = jn * 16 + l16;
#pragma unroll
                for (int kc = 0; kc < 4; ++kc) {
                    bf16x8 b = *(const bf16x8*)&sK[krow * 128 + (((kc * 4 + quad) ^ l16) << 3)];
                    S0[jn] = __builtin_amdgcn_mfma_f32_16x16x32_bf16(qf0[kc], b, S0[jn], 0, 0, 0);
                    S1[jn] = __builtin_amdgcn_mfma_f32_16x16x32_bf16(qf1[kc], b, S1[jn], 0, 0, 0);
                }
            }
            const int masked = (st == nk_w - 1);
            SM_SET(S0, mrow0, lrow0, O0, qbase, masked, s0);
            SM_SET(S1, mrow1, lrow1, O1, qbase + 16, masked, s0);

#pragma unroll
            for (int jn = 0; jn < 8; ++jn)
#pragma unroll
                for (int r = 0; r < 4; ++r) {
                    int prow = quad * 4 + r;
                    int pcol = jn * 16 + l16;
                    int off = (pcol & 7) | ((((pcol >> 3) ^ prow) & 15) << 3);
                    sPw[prow * 128 + off]        = f2bf(S0[jn][r]);
                    sPw[(16 + prow) * 128 + off] = f2bf(S1[jn][r]);
                }
            bf16x8 pf0[4], pf1[4];
#pragma unroll
            for (int ksv = 0; ksv < 4; ++ksv) {
                pf0[ksv] = *(const bf16x8*)&sPw[l16 * 128 + (((ksv * 4 + quad) ^ l16) << 3)];
                pf1[ksv] = *(const bf16x8*)&sPw[(16 + l16) * 128 + (((ksv * 4 + quad) ^ l16) << 3)];
            }
#pragma unroll
            for (int hj = 0; hj < 8; ++hj) {
                int vrow = hj * 16 + l16;
#pragma unroll
                for (int ksv = 0; ksv < 4; ++ksv) {
                    bf16x8 b = *(const bf16x8*)&sV[vrow * 128 + (((ksv * 4 + quad) ^ l16) << 3)];
                    O0[hj] = __builtin_amdgcn_mfma_f32_16x16x32_bf16(pf0[ksv], b, O0[hj], 0, 0, 0);
                    O1[hj] = __builtin_amdgcn_mfma_f32_16x16x32_bf16(pf1[ksv], b, O1[hj], 0, 0, 0);
                }
            }
        }
    }
#undef SM_SET

#pragma unroll
    for (int set = 0; set < 2; ++set) {
        float inv[4];
#pragma unroll
        for (int r = 0; r < 4; ++r)
            inv[r] = 1.0f / (set ? lrow1[r] : lrow0[r]);
#pragma unroll
        for (int hj = 0; hj < 8; ++hj)
#pragma unroll
            for (int r = 0; r < 4; ++r) {
                float v = (set ? O1[hj][r] : O0[hj][r]) * inv[r];
                sPw[(quad * 4 + r) * 132 + hj * 16 + l16] = f2bf(v);
            }
#pragma unroll
        for (int it = 0; it < 4; ++it) {
            int slot = it * 64 + lane, rloc = slot >> 4, cl = slot & 15;
            bf16x8 v = *(const bf16x8*)&sPw[rloc * 132 + cl * 8];
            int R = qbase + set * 16 + rloc;
            size_t dst = (size_t)R * 4096 + n * 128 + ((cl & 8) << 3) + (((cl & 7) ^ (R & 7)) << 3);
            *(uint4*)&att[dst] = *(uint4*)&v;
        }
    }
}

// ============================================================================
extern "C" void kernel_launch(void* const* d_in, const int* in_sizes, int n_in,
                              void* d_out, int out_size, void* d_ws, size_t ws_size,
                              hipStream_t stream) {
    const float* x   = (const float*)d_in[0];
    const int*   sp  = (const int*)d_in[1];
    const float* qw  = (const float*)d_in[3];
    const float* kvw = (const float*)d_in[4];
    const float* ow  = (const float*)d_in[5];
    const float* qsc = (const float*)d_in[6];
    const float* ksc = (const float*)d_in[7];
    float* out = (float*)d_out;

    char* ws = (char*)d_ws;
    uint16_t* xb   = (uint16_t*)(ws);
    uint16_t* Wt   = (uint16_t*)(ws + (size_t)(16u << 20));
    uint16_t* Qb   = (uint16_t*)(ws + (size_t)(64u << 20));
    uint16_t* Kb   = (uint16_t*)(ws + (size_t)(80u << 20));
    uint16_t* Vtb  = (uint16_t*)(ws + (size_t)(84u << 20));
    uint16_t* att  = (uint16_t*)(ws);                           // over dead xb

    // Ot placement: fused prep needs a region disjoint from gemm1's working
    // set [0,88M). Use [88,120M) when the workspace allows; else fall back to
    // the round-7 overlay on dead Wt at [16,48M), written by a separate
    // kernel AFTER gemm1 completes.
    const bool fused = ws_size >= ((size_t)120u << 20);
    uint16_t* Ot = (uint16_t*)(ws + ((size_t)(fused ? 88u : 16u) << 20));

    static bool attr_done = false;
    if (!attr_done) {
        hipFuncSetAttribute(reinterpret_cast<const void*>(k_gemm_qkv),
                            hipFuncAttributeMaxDynamicSharedMemorySize, 137216);
        hipFuncSetAttribute(reinterpret_cast<const void*>(k_gemm2b),
                            hipFuncAttributeMaxDynamicSharedMemorySize, 65536);
        hipFuncSetAttribute(reinterpret_cast<const void*>(k_attn),
                            hipFuncAttributeMaxDynamicSharedMemorySize, 131072);
        attr_done = true;
    }

    k_prep <<<10240, 256, 0, stream>>>(x, xb, qw, kvw, Wt);
    if (fused) {
        k_gemm_qkv <<<dim3(32, 8), 512, 137216, stream>>>(xb, Wt, sp, qsc, ksc,
                                                          Qb, Kb, Vtb, ow, Ot);
    } else {
        k_gemm_qkv <<<dim3(24, 8), 512, 137216, stream>>>(xb, Wt, sp, qsc, ksc,
                                                          Qb, Kb, Vtb, ow, Ot);
        k_prep_ot  <<<dim3(64, 2, 32), 256, 0, stream>>>(ow, Ot);
    }
    k_attn   <<<dim3(8, 32), 512, 131072, stream>>>(Qb, Kb, Vtb, att);
    k_gemm2b <<<dim3(32, 16), 256, 65536, stream>>>(att, Ot, out);
}